// Round 1
// baseline (2566.775 us; speedup 1.0000x reference)
//
#include <hip/hip_runtime.h>

#define HID 128
#define NB 16   // nodes per matmul block

// ---------------- degree accumulation over edges ----------------
__global__ void gc_degree(const int* __restrict__ src, const int* __restrict__ dst,
                          float* __restrict__ deg_out, float* __restrict__ deg_in,
                          int n_edges) {
    int e = blockIdx.x * blockDim.x + threadIdx.x;
    if (e < n_edges) {
        atomicAdd(&deg_out[src[e]], 1.0f);
        atomicAdd(&deg_in[dst[e]], 1.0f);
    }
}

// ---------------- per-node: norms + graph counts ----------------
__global__ void gc_node(const float* __restrict__ deg_out, const float* __restrict__ deg_in,
                        float* __restrict__ norm_s, float* __restrict__ norm_d,
                        const int* __restrict__ gid, float* __restrict__ counts,
                        int n_nodes) {
    int n = blockIdx.x * blockDim.x + threadIdx.x;
    if (n < n_nodes) {
        norm_s[n] = 1.0f / sqrtf(fmaxf(deg_out[n], 1.0f));
        norm_d[n] = 1.0f / sqrtf(fmaxf(deg_in[n], 1.0f));
        atomicAdd(&counts[gid[n]], 1.0f);
    }
}

// ---------------- out[n,:] = (X[n,:] * norm_s[n]) @ W ----------------
__global__ void gc_matmul(const float* __restrict__ X, const float* __restrict__ norm_s,
                          const float* __restrict__ W, float* __restrict__ out,
                          int n_nodes) {
    __shared__ float xs[NB][HID];
    int c = threadIdx.x;          // 0..127
    int n0 = blockIdx.x * NB;
    #pragma unroll
    for (int i = 0; i < NB; ++i) {
        int n = n0 + i;
        float v = 0.0f;
        if (n < n_nodes) v = X[(size_t)n * HID + c] * norm_s[n];
        xs[i][c] = v;
    }
    __syncthreads();
    float acc[NB];
    #pragma unroll
    for (int i = 0; i < NB; ++i) acc[i] = 0.0f;
    for (int k = 0; k < HID; ++k) {
        float wv = W[(size_t)k * HID + c];
        #pragma unroll
        for (int i = 0; i < NB; ++i) acc[i] += xs[i][k] * wv;  // xs broadcast read
    }
    #pragma unroll
    for (int i = 0; i < NB; ++i) {
        int n = n0 + i;
        if (n < n_nodes) out[(size_t)n * HID + c] = acc[i];
    }
}

// ---------------- agg[dst[e],:] += hw[src[e],:] ----------------
__global__ void gc_scatter(const float* __restrict__ HW, const int* __restrict__ src,
                           const int* __restrict__ dst, float* __restrict__ agg,
                           int n_edges) {
    int idx = blockIdx.x * blockDim.x + threadIdx.x;   // over n_edges*32
    int total = n_edges * 32;
    if (idx >= total) return;
    int e = idx >> 5;
    int q = (idx & 31) << 2;          // float4 column offset
    int s = src[e], d = dst[e];
    const float4 v = *reinterpret_cast<const float4*>(HW + (size_t)s * HID + q);
    float* base = agg + (size_t)d * HID + q;
    atomicAdd(base + 0, v.x);
    atomicAdd(base + 1, v.y);
    atomicAdd(base + 2, v.z);
    atomicAdd(base + 3, v.w);
}

// ---------------- h = relu(agg * norm_d[n] + b) (in place) ----------------
__global__ void gc_postnorm(float* __restrict__ agg, const float* __restrict__ norm_d,
                            const float* __restrict__ b, int n_nodes) {
    int idx = blockIdx.x * blockDim.x + threadIdx.x;   // over n_nodes*32
    int total = n_nodes * 32;
    if (idx >= total) return;
    int n = idx >> 5;
    int q = (idx & 31) << 2;
    float nd = norm_d[n];
    float4 v = *reinterpret_cast<float4*>(agg + (size_t)n * HID + q);
    const float4 bv = *reinterpret_cast<const float4*>(b + q);
    v.x = fmaxf(v.x * nd + bv.x, 0.0f);
    v.y = fmaxf(v.y * nd + bv.y, 0.0f);
    v.z = fmaxf(v.z * nd + bv.z, 0.0f);
    v.w = fmaxf(v.w * nd + bv.w, 0.0f);
    *reinterpret_cast<float4*>(agg + (size_t)n * HID + q) = v;
}

// ---------------- per-graph sums ----------------
__global__ void gc_pool(const float* __restrict__ h2, const int* __restrict__ gid,
                        float* __restrict__ sums, int n_nodes) {
    int idx = blockIdx.x * blockDim.x + threadIdx.x;   // over n_nodes*32
    int total = n_nodes * 32;
    if (idx >= total) return;
    int n = idx >> 5;
    int q = (idx & 31) << 2;
    int g = gid[n];
    const float4 v = *reinterpret_cast<const float4*>(h2 + (size_t)n * HID + q);
    float* base = sums + (size_t)g * HID + q;
    atomicAdd(base + 0, v.x);
    atomicAdd(base + 1, v.y);
    atomicAdd(base + 2, v.z);
    atomicAdd(base + 3, v.w);
}

// ---------------- fused MLP head: one block per graph ----------------
__global__ void gc_mlp(const float* __restrict__ sums, const float* __restrict__ counts,
                       const float* __restrict__ Wc1, const float* __restrict__ bc1,
                       const float* __restrict__ Wc2, const float* __restrict__ bc2,
                       const float* __restrict__ Wc3, const float* __restrict__ bc3,
                       float* __restrict__ out) {
    int g = blockIdx.x;
    int c = threadIdx.x;   // 0..127
    __shared__ float x[HID];
    __shared__ float y[HID];
    __shared__ float red[HID];
    float inv = 1.0f / fmaxf(counts[g], 1.0f);
    x[c] = sums[(size_t)g * HID + c] * inv;
    __syncthreads();
    float a = bc1[c];
    for (int k = 0; k < HID; ++k) a += x[k] * Wc1[(size_t)k * HID + c];
    y[c] = fmaxf(a, 0.0f);
    __syncthreads();
    float a2 = bc2[c];
    for (int k = 0; k < HID; ++k) a2 += y[k] * Wc2[(size_t)k * HID + c];
    float z = fmaxf(a2, 0.0f);
    red[c] = z * Wc3[c];    // Wc3 is [128,1]
    __syncthreads();
    for (int s = 64; s > 0; s >>= 1) {
        if (c < s) red[c] += red[c + s];
        __syncthreads();
    }
    if (c == 0) out[g] = red[0] + bc3[0];
}

extern "C" void kernel_launch(void* const* d_in, const int* in_sizes, int n_in,
                              void* d_out, int out_size, void* d_ws, size_t ws_size,
                              hipStream_t stream) {
    const float* h    = (const float*)d_in[0];
    const int*   src  = (const int*)d_in[1];
    const int*   dst  = (const int*)d_in[2];
    const int*   gid  = (const int*)d_in[3];
    const float* W1   = (const float*)d_in[4];
    const float* b1   = (const float*)d_in[5];
    const float* W2   = (const float*)d_in[6];
    const float* b2   = (const float*)d_in[7];
    const float* Wc1  = (const float*)d_in[8];
    const float* bc1  = (const float*)d_in[9];
    const float* Wc2  = (const float*)d_in[10];
    const float* bc2  = (const float*)d_in[11];
    const float* Wc3  = (const float*)d_in[12];
    const float* bc3  = (const float*)d_in[13];
    float* out = (float*)d_out;

    const int n_nodes = in_sizes[0] / HID;   // 40000
    const int n_edges = in_sizes[1];         // 640000
    const int n_graphs = 256;

    float* ws = (float*)d_ws;
    // workspace layout (floats)
    float* deg_out = ws;                 // 40000
    float* deg_in  = ws + 40000;         // 40000
    float* norm_s  = ws + 80000;         // 40000
    float* norm_d  = ws + 120000;        // 40000
    float* sums    = ws + 160000;        // 256*128 = 32768
    float* counts  = ws + 192768;        // 256
    float* buf0    = ws + 196608;        // 5,120,000  (hw)
    float* buf1    = buf0 + (size_t)n_nodes * HID;  // 5,120,000 (agg / h1 / h2)

    const size_t feat_bytes = (size_t)n_nodes * HID * sizeof(float);

    // zero: degrees (contiguous 80000), sums+counts (contiguous 33024)
    hipMemsetAsync(deg_out, 0, 80000 * sizeof(float), stream);
    hipMemsetAsync(sums, 0, 33024 * sizeof(float), stream);

    // degrees
    gc_degree<<<(n_edges + 255) / 256, 256, 0, stream>>>(src, dst, deg_out, deg_in, n_edges);
    // norms + graph counts
    gc_node<<<(n_nodes + 255) / 256, 256, 0, stream>>>(deg_out, deg_in, norm_s, norm_d,
                                                       gid, counts, n_nodes);

    const int mm_grid = (n_nodes + NB - 1) / NB;
    const int ew_grid = (n_nodes * 32 + 255) / 256;    // element-wise over node feats
    const int sc_grid = (n_edges * 32 + 255) / 256;    // scatter over edge feats

    // ----- layer 1 -----
    gc_matmul<<<mm_grid, HID, 0, stream>>>(h, norm_s, W1, buf0, n_nodes);
    hipMemsetAsync(buf1, 0, feat_bytes, stream);
    gc_scatter<<<sc_grid, 256, 0, stream>>>(buf0, src, dst, buf1, n_edges);
    gc_postnorm<<<ew_grid, 256, 0, stream>>>(buf1, norm_d, b1, n_nodes);

    // ----- layer 2 -----
    gc_matmul<<<mm_grid, HID, 0, stream>>>(buf1, norm_s, W2, buf0, n_nodes);
    hipMemsetAsync(buf1, 0, feat_bytes, stream);
    gc_scatter<<<sc_grid, 256, 0, stream>>>(buf0, src, dst, buf1, n_edges);
    gc_postnorm<<<ew_grid, 256, 0, stream>>>(buf1, norm_d, b2, n_nodes);

    // ----- pooling + MLP head -----
    gc_pool<<<ew_grid, 256, 0, stream>>>(buf1, gid, sums, n_nodes);
    gc_mlp<<<n_graphs, HID, 0, stream>>>(sums, counts, Wc1, bc1, Wc2, bc2, Wc3, bc3, out);
}

// Round 2
// 629.036 us; speedup vs baseline: 4.0805x; 4.0805x over previous
//
#include <hip/hip_runtime.h>

#define HID 128
#define NB 16   // nodes per matmul block

// ---------------- int degree histograms over edges ----------------
__global__ void gc_degree(const int* __restrict__ src, const int* __restrict__ dst,
                          int* __restrict__ ideg_out, int* __restrict__ ideg_in,
                          int n_edges) {
    int e = blockIdx.x * blockDim.x + threadIdx.x;
    if (e < n_edges) {
        atomicAdd(&ideg_out[src[e]], 1);
        atomicAdd(&ideg_in[dst[e]], 1);
    }
}

// ---------------- single-block exclusive scan of deg_in -> row_ptr, cursor ----
__global__ void gc_scan(const int* __restrict__ deg, int* __restrict__ row_ptr,
                        int* __restrict__ cursor, int n_nodes) {
    const int T = 1024;
    int t = threadIdx.x;
    int per = (n_nodes + T - 1) / T;
    int start = t * per;
    int end = min(start + per, n_nodes);
    int local = 0;
    for (int i = start; i < end; ++i) local += deg[i];
    __shared__ int part[T];
    part[t] = local;
    __syncthreads();
    for (int off = 1; off < T; off <<= 1) {
        int v = (t >= off) ? part[t - off] : 0;
        __syncthreads();
        part[t] += v;
        __syncthreads();
    }
    int run = (t == 0) ? 0 : part[t - 1];   // exclusive prefix of this thread's chunk
    for (int i = start; i < end; ++i) {
        cursor[i] = run;          // row start (doubles as fill cursor)
        run += deg[i];
        row_ptr[i + 1] = run;
    }
    if (t == 0) row_ptr[0] = 0;
}

// ---------------- per-node norms + per-graph counts ----------------
__global__ void gc_node(const int* __restrict__ ideg_out, const int* __restrict__ ideg_in,
                        float* __restrict__ norm_s, float* __restrict__ norm_d,
                        const int* __restrict__ gid, float* __restrict__ counts,
                        int n_nodes) {
    int n = blockIdx.x * blockDim.x + threadIdx.x;
    if (n < n_nodes) {
        norm_s[n] = rsqrtf(fmaxf((float)ideg_out[n], 1.0f));
        norm_d[n] = rsqrtf(fmaxf((float)ideg_in[n], 1.0f));
        atomicAdd(&counts[gid[n]], 1.0f);
    }
}

// ---------------- CSR fill: edge_src bucketed by dst ----------------
__global__ void gc_fill(const int* __restrict__ src, const int* __restrict__ dst,
                        int* __restrict__ cursor, int* __restrict__ edge_src,
                        int n_edges) {
    int e = blockIdx.x * blockDim.x + threadIdx.x;
    if (e < n_edges) {
        int pos = atomicAdd(&cursor[dst[e]], 1);
        edge_src[pos] = src[e];
    }
}

// ---------------- out[n,:] = (X[n,:] * norm_s[n]) @ W ----------------
__global__ void gc_matmul(const float* __restrict__ X, const float* __restrict__ norm_s,
                          const float* __restrict__ W, float* __restrict__ out,
                          int n_nodes) {
    __shared__ float xs[NB][HID];
    int c = threadIdx.x;          // 0..127
    int n0 = blockIdx.x * NB;
    #pragma unroll
    for (int i = 0; i < NB; ++i) {
        int n = n0 + i;
        float v = 0.0f;
        if (n < n_nodes) v = X[(size_t)n * HID + c] * norm_s[n];
        xs[i][c] = v;
    }
    __syncthreads();
    float acc[NB];
    #pragma unroll
    for (int i = 0; i < NB; ++i) acc[i] = 0.0f;
    for (int k = 0; k < HID; ++k) {
        float wv = W[(size_t)k * HID + c];
        #pragma unroll
        for (int i = 0; i < NB; ++i) acc[i] += xs[i][k] * wv;  // xs broadcast read
    }
    #pragma unroll
    for (int i = 0; i < NB; ++i) {
        int n = n0 + i;
        if (n < n_nodes) out[(size_t)n * HID + c] = acc[i];
    }
}

// ------- gather + norm + bias + relu: 32 lanes per dst node, float4 cols -------
__global__ void gc_gather(const float* __restrict__ HW, const int* __restrict__ row_ptr,
                          const int* __restrict__ edge_src, const float* __restrict__ norm_d,
                          const float* __restrict__ b, float* __restrict__ out,
                          int n_nodes) {
    int node = blockIdx.x * 8 + (threadIdx.x >> 5);
    if (node >= n_nodes) return;
    int q = (threadIdx.x & 31) << 2;          // float4 column offset
    int beg = row_ptr[node], end = row_ptr[node + 1];
    float ax = 0.f, ay = 0.f, az = 0.f, aw = 0.f;
    for (int e = beg; e < end; ++e) {
        int s = edge_src[e];                  // broadcast across the 32 lanes
        const float4 v = *reinterpret_cast<const float4*>(HW + (size_t)s * HID + q);
        ax += v.x; ay += v.y; az += v.z; aw += v.w;
    }
    float nd = norm_d[node];
    const float4 bv = *reinterpret_cast<const float4*>(b + q);
    float4 r;
    r.x = fmaxf(ax * nd + bv.x, 0.0f);
    r.y = fmaxf(ay * nd + bv.y, 0.0f);
    r.z = fmaxf(az * nd + bv.z, 0.0f);
    r.w = fmaxf(aw * nd + bv.w, 0.0f);
    *reinterpret_cast<float4*>(out + (size_t)node * HID + q) = r;
}

// ---------------- per-graph sums ----------------
__global__ void gc_pool(const float* __restrict__ h2, const int* __restrict__ gid,
                        float* __restrict__ sums, int n_nodes) {
    int idx = blockIdx.x * blockDim.x + threadIdx.x;   // over n_nodes*32
    int total = n_nodes * 32;
    if (idx >= total) return;
    int n = idx >> 5;
    int q = (idx & 31) << 2;
    int g = gid[n];
    const float4 v = *reinterpret_cast<const float4*>(h2 + (size_t)n * HID + q);
    float* base = sums + (size_t)g * HID + q;
    atomicAdd(base + 0, v.x);
    atomicAdd(base + 1, v.y);
    atomicAdd(base + 2, v.z);
    atomicAdd(base + 3, v.w);
}

// ---------------- fused MLP head: one block per graph ----------------
__global__ void gc_mlp(const float* __restrict__ sums, const float* __restrict__ counts,
                       const float* __restrict__ Wc1, const float* __restrict__ bc1,
                       const float* __restrict__ Wc2, const float* __restrict__ bc2,
                       const float* __restrict__ Wc3, const float* __restrict__ bc3,
                       float* __restrict__ out) {
    int g = blockIdx.x;
    int c = threadIdx.x;   // 0..127
    __shared__ float x[HID];
    __shared__ float y[HID];
    __shared__ float red[HID];
    float inv = 1.0f / fmaxf(counts[g], 1.0f);
    x[c] = sums[(size_t)g * HID + c] * inv;
    __syncthreads();
    float a = bc1[c];
    for (int k = 0; k < HID; ++k) a += x[k] * Wc1[(size_t)k * HID + c];
    y[c] = fmaxf(a, 0.0f);
    __syncthreads();
    float a2 = bc2[c];
    for (int k = 0; k < HID; ++k) a2 += y[k] * Wc2[(size_t)k * HID + c];
    float z = fmaxf(a2, 0.0f);
    red[c] = z * Wc3[c];    // Wc3 is [128,1]
    __syncthreads();
    for (int s = 64; s > 0; s >>= 1) {
        if (c < s) red[c] += red[c + s];
        __syncthreads();
    }
    if (c == 0) out[g] = red[0] + bc3[0];
}

extern "C" void kernel_launch(void* const* d_in, const int* in_sizes, int n_in,
                              void* d_out, int out_size, void* d_ws, size_t ws_size,
                              hipStream_t stream) {
    const float* h    = (const float*)d_in[0];
    const int*   src  = (const int*)d_in[1];
    const int*   dst  = (const int*)d_in[2];
    const int*   gid  = (const int*)d_in[3];
    const float* W1   = (const float*)d_in[4];
    const float* b1   = (const float*)d_in[5];
    const float* W2   = (const float*)d_in[6];
    const float* b2   = (const float*)d_in[7];
    const float* Wc1  = (const float*)d_in[8];
    const float* bc1  = (const float*)d_in[9];
    const float* Wc2  = (const float*)d_in[10];
    const float* bc2  = (const float*)d_in[11];
    const float* Wc3  = (const float*)d_in[12];
    const float* bc3  = (const float*)d_in[13];
    float* out = (float*)d_out;

    const int n_nodes  = in_sizes[0] / HID;   // 40000
    const int n_edges  = in_sizes[1];         // 640000
    const int n_graphs = 256;

    char* wsb = (char*)d_ws;
    size_t off = 0;
    auto alloc = [&](size_t elems) { void* p = wsb + off; off += elems * 4; return p; };

    int*   ideg_out = (int*)alloc(n_nodes);
    int*   ideg_in  = (int*)alloc(n_nodes);
    float* norm_s   = (float*)alloc(n_nodes);
    float* norm_d   = (float*)alloc(n_nodes);
    int*   row_ptr  = (int*)alloc(n_nodes + 1);
    int*   cursor   = (int*)alloc(n_nodes);
    int*   edge_src = (int*)alloc(n_edges);
    float* sums     = (float*)alloc(n_graphs * HID);
    float* counts   = (float*)alloc(n_graphs);
    float* buf0     = (float*)alloc((size_t)n_nodes * HID);
    float* buf1     = (float*)alloc((size_t)n_nodes * HID);

    // zero: int degree histograms; pool sums+counts
    hipMemsetAsync(ideg_out, 0, 2 * n_nodes * sizeof(int), stream);
    hipMemsetAsync(sums, 0, (n_graphs * HID + n_graphs) * sizeof(float), stream);

    gc_degree<<<(n_edges + 255) / 256, 256, 0, stream>>>(src, dst, ideg_out, ideg_in, n_edges);
    gc_scan<<<1, 1024, 0, stream>>>(ideg_in, row_ptr, cursor, n_nodes);
    gc_node<<<(n_nodes + 255) / 256, 256, 0, stream>>>(ideg_out, ideg_in, norm_s, norm_d,
                                                       gid, counts, n_nodes);
    gc_fill<<<(n_edges + 255) / 256, 256, 0, stream>>>(src, dst, cursor, edge_src, n_edges);

    const int mm_grid = (n_nodes + NB - 1) / NB;
    const int ga_grid = (n_nodes + 7) / 8;
    const int ew_grid = (n_nodes * 32 + 255) / 256;

    // ----- layer 1 -----
    gc_matmul<<<mm_grid, HID, 0, stream>>>(h, norm_s, W1, buf0, n_nodes);
    gc_gather<<<ga_grid, 256, 0, stream>>>(buf0, row_ptr, edge_src, norm_d, b1, buf1, n_nodes);

    // ----- layer 2 -----
    gc_matmul<<<mm_grid, HID, 0, stream>>>(buf1, norm_s, W2, buf0, n_nodes);
    gc_gather<<<ga_grid, 256, 0, stream>>>(buf0, row_ptr, edge_src, norm_d, b2, buf1, n_nodes);

    // ----- pooling + MLP head -----
    gc_pool<<<ew_grid, 256, 0, stream>>>(buf1, gid, sums, n_nodes);
    gc_mlp<<<n_graphs, HID, 0, stream>>>(sums, counts, Wc1, bc1, Wc2, bc2, Wc3, bc3, out);
}

// Round 3
// 485.427 us; speedup vs baseline: 5.2877x; 1.2958x over previous
//
#include <hip/hip_runtime.h>

#define HID 128
#define NB 16   // nodes per matmul block

// ---------------- int degree histograms over edges ----------------
__global__ void gc_degree(const int* __restrict__ src, const int* __restrict__ dst,
                          int* __restrict__ ideg_out, int* __restrict__ ideg_in,
                          int n_edges) {
    int e = blockIdx.x * blockDim.x + threadIdx.x;
    if (e < n_edges) {
        atomicAdd(&ideg_out[src[e]], 1);
        atomicAdd(&ideg_in[dst[e]], 1);
    }
}

// ---------------- single-block exclusive scan of deg_in -> row_ptr, cursor ----
__global__ void gc_scan(const int* __restrict__ deg, int* __restrict__ row_ptr,
                        int* __restrict__ cursor, int n_nodes) {
    const int T = 1024;
    int t = threadIdx.x;
    int per = (n_nodes + T - 1) / T;
    int start = t * per;
    int end = min(start + per, n_nodes);
    int local = 0;
    for (int i = start; i < end; ++i) local += deg[i];
    __shared__ int part[T];
    part[t] = local;
    __syncthreads();
    for (int off = 1; off < T; off <<= 1) {
        int v = (t >= off) ? part[t - off] : 0;
        __syncthreads();
        part[t] += v;
        __syncthreads();
    }
    int run = (t == 0) ? 0 : part[t - 1];   // exclusive prefix of this thread's chunk
    for (int i = start; i < end; ++i) {
        cursor[i] = run;          // row start (doubles as fill cursor)
        run += deg[i];
        row_ptr[i + 1] = run;
    }
    if (t == 0) row_ptr[0] = 0;
}

// ---------------- per-node norms ----------------
__global__ void gc_node(const int* __restrict__ ideg_out, const int* __restrict__ ideg_in,
                        float* __restrict__ norm_s, float* __restrict__ norm_d,
                        int n_nodes) {
    int n = blockIdx.x * blockDim.x + threadIdx.x;
    if (n < n_nodes) {
        norm_s[n] = rsqrtf(fmaxf((float)ideg_out[n], 1.0f));
        norm_d[n] = rsqrtf(fmaxf((float)ideg_in[n], 1.0f));
    }
}

// ---------------- graph_ptr via binary search (gid is sorted) ----------------
__global__ void gc_gptr(const int* __restrict__ gid, int* __restrict__ gptr,
                        int n_nodes, int n_graphs) {
    int g = threadIdx.x;                      // 0..255
    int lo = 0, hi = n_nodes;
    while (lo < hi) {                         // lower_bound(gid, g)
        int mid = (lo + hi) >> 1;
        if (gid[mid] < g) lo = mid + 1; else hi = mid;
    }
    gptr[g] = lo;
    if (g == 0) gptr[n_graphs] = n_nodes;
}

// ---------------- CSR fill: edge_src bucketed by dst ----------------
__global__ void gc_fill(const int* __restrict__ src, const int* __restrict__ dst,
                        int* __restrict__ cursor, int* __restrict__ edge_src,
                        int n_edges) {
    int e = blockIdx.x * blockDim.x + threadIdx.x;
    if (e < n_edges) {
        int pos = atomicAdd(&cursor[dst[e]], 1);
        edge_src[pos] = src[e];
    }
}

// ---------------- out[n,:] = (X[n,:] * norm_s[n]) @ W ----------------
__global__ void gc_matmul(const float* __restrict__ X, const float* __restrict__ norm_s,
                          const float* __restrict__ W, float* __restrict__ out,
                          int n_nodes) {
    __shared__ float xs[NB][HID];
    int c = threadIdx.x;          // 0..127
    int n0 = blockIdx.x * NB;
    #pragma unroll
    for (int i = 0; i < NB; ++i) {
        int n = n0 + i;
        float v = 0.0f;
        if (n < n_nodes) v = X[(size_t)n * HID + c] * norm_s[n];
        xs[i][c] = v;
    }
    __syncthreads();
    float acc[NB];
    #pragma unroll
    for (int i = 0; i < NB; ++i) acc[i] = 0.0f;
    for (int k = 0; k < HID; ++k) {
        float wv = W[(size_t)k * HID + c];
        #pragma unroll
        for (int i = 0; i < NB; ++i) acc[i] += xs[i][k] * wv;  // xs broadcast read
    }
    #pragma unroll
    for (int i = 0; i < NB; ++i) {
        int n = n0 + i;
        if (n < n_nodes) out[(size_t)n * HID + c] = acc[i];
    }
}

// ------- gather + norm + bias + relu: 32 lanes per dst node, float4 cols -------
__global__ void gc_gather(const float* __restrict__ HW, const int* __restrict__ row_ptr,
                          const int* __restrict__ edge_src, const float* __restrict__ norm_d,
                          const float* __restrict__ b, float* __restrict__ out,
                          int n_nodes) {
    int node = blockIdx.x * 8 + (threadIdx.x >> 5);
    if (node >= n_nodes) return;
    int q = (threadIdx.x & 31) << 2;          // float4 column offset
    int beg = row_ptr[node], end = row_ptr[node + 1];
    float ax = 0.f, ay = 0.f, az = 0.f, aw = 0.f;
    int e = beg;
    for (; e + 1 < end; e += 2) {             // 2 independent rows in flight
        int s0 = edge_src[e], s1 = edge_src[e + 1];
        const float4 v0 = *reinterpret_cast<const float4*>(HW + (size_t)s0 * HID + q);
        const float4 v1 = *reinterpret_cast<const float4*>(HW + (size_t)s1 * HID + q);
        ax += v0.x + v1.x; ay += v0.y + v1.y;
        az += v0.z + v1.z; aw += v0.w + v1.w;
    }
    if (e < end) {
        int s0 = edge_src[e];
        const float4 v0 = *reinterpret_cast<const float4*>(HW + (size_t)s0 * HID + q);
        ax += v0.x; ay += v0.y; az += v0.z; aw += v0.w;
    }
    float nd = norm_d[node];
    const float4 bv = *reinterpret_cast<const float4*>(b + q);
    float4 r;
    r.x = fmaxf(ax * nd + bv.x, 0.0f);
    r.y = fmaxf(ay * nd + bv.y, 0.0f);
    r.z = fmaxf(az * nd + bv.z, 0.0f);
    r.w = fmaxf(aw * nd + bv.w, 0.0f);
    *reinterpret_cast<float4*>(out + (size_t)node * HID + q) = r;
}

// ------- fused mean-pool + MLP head: one block per graph, no atomics -------
__global__ void gc_pool_mlp(const float* __restrict__ h2, const int* __restrict__ gptr,
                            const float* __restrict__ Wc1, const float* __restrict__ bc1,
                            const float* __restrict__ Wc2, const float* __restrict__ bc2,
                            const float* __restrict__ Wc3, const float* __restrict__ bc3,
                            float* __restrict__ out) {
    int g = blockIdx.x;
    int c = threadIdx.x;   // 0..127
    int beg = gptr[g], end = gptr[g + 1];
    float s = 0.0f;
    for (int n = beg; n < end; ++n) s += h2[(size_t)n * HID + c];  // coalesced rows
    float inv = 1.0f / fmaxf((float)(end - beg), 1.0f);
    __shared__ float x[HID];
    __shared__ float y[HID];
    __shared__ float red[HID];
    x[c] = s * inv;
    __syncthreads();
    float a = bc1[c];
    for (int k = 0; k < HID; ++k) a += x[k] * Wc1[(size_t)k * HID + c];
    y[c] = fmaxf(a, 0.0f);
    __syncthreads();
    float a2 = bc2[c];
    for (int k = 0; k < HID; ++k) a2 += y[k] * Wc2[(size_t)k * HID + c];
    float z = fmaxf(a2, 0.0f);
    red[c] = z * Wc3[c];    // Wc3 is [128,1]
    __syncthreads();
    for (int sred = 64; sred > 0; sred >>= 1) {
        if (c < sred) red[c] += red[c + sred];
        __syncthreads();
    }
    if (c == 0) out[g] = red[0] + bc3[0];
}

extern "C" void kernel_launch(void* const* d_in, const int* in_sizes, int n_in,
                              void* d_out, int out_size, void* d_ws, size_t ws_size,
                              hipStream_t stream) {
    const float* h    = (const float*)d_in[0];
    const int*   src  = (const int*)d_in[1];
    const int*   dst  = (const int*)d_in[2];
    const int*   gid  = (const int*)d_in[3];
    const float* W1   = (const float*)d_in[4];
    const float* b1   = (const float*)d_in[5];
    const float* W2   = (const float*)d_in[6];
    const float* b2   = (const float*)d_in[7];
    const float* Wc1  = (const float*)d_in[8];
    const float* bc1  = (const float*)d_in[9];
    const float* Wc2  = (const float*)d_in[10];
    const float* bc2  = (const float*)d_in[11];
    const float* Wc3  = (const float*)d_in[12];
    const float* bc3  = (const float*)d_in[13];
    float* out = (float*)d_out;

    const int n_nodes  = in_sizes[0] / HID;   // 40000
    const int n_edges  = in_sizes[1];         // 640000
    const int n_graphs = 256;

    char* wsb = (char*)d_ws;
    size_t off = 0;
    auto alloc = [&](size_t elems) { void* p = wsb + off; off += elems * 4; return p; };

    int*   ideg_out = (int*)alloc(n_nodes);
    int*   ideg_in  = (int*)alloc(n_nodes);
    float* norm_s   = (float*)alloc(n_nodes);
    float* norm_d   = (float*)alloc(n_nodes);
    int*   row_ptr  = (int*)alloc(n_nodes + 1);
    int*   cursor   = (int*)alloc(n_nodes);
    int*   edge_src = (int*)alloc(n_edges);
    int*   gptr     = (int*)alloc(n_graphs + 1);
    float* buf0     = (float*)alloc((size_t)n_nodes * HID);
    float* buf1     = (float*)alloc((size_t)n_nodes * HID);

    // zero the int degree histograms only
    hipMemsetAsync(ideg_out, 0, 2 * n_nodes * sizeof(int), stream);

    gc_degree<<<(n_edges + 255) / 256, 256, 0, stream>>>(src, dst, ideg_out, ideg_in, n_edges);
    gc_scan<<<1, 1024, 0, stream>>>(ideg_in, row_ptr, cursor, n_nodes);
    gc_node<<<(n_nodes + 255) / 256, 256, 0, stream>>>(ideg_out, ideg_in, norm_s, norm_d, n_nodes);
    gc_gptr<<<1, n_graphs, 0, stream>>>(gid, gptr, n_nodes, n_graphs);
    gc_fill<<<(n_edges + 255) / 256, 256, 0, stream>>>(src, dst, cursor, edge_src, n_edges);

    const int mm_grid = (n_nodes + NB - 1) / NB;
    const int ga_grid = (n_nodes + 7) / 8;

    // ----- layer 1 -----
    gc_matmul<<<mm_grid, HID, 0, stream>>>(h, norm_s, W1, buf0, n_nodes);
    gc_gather<<<ga_grid, 256, 0, stream>>>(buf0, row_ptr, edge_src, norm_d, b1, buf1, n_nodes);

    // ----- layer 2 -----
    gc_matmul<<<mm_grid, HID, 0, stream>>>(buf1, norm_s, W2, buf0, n_nodes);
    gc_gather<<<ga_grid, 256, 0, stream>>>(buf0, row_ptr, edge_src, norm_d, b2, buf1, n_nodes);

    // ----- fused pooling + MLP head -----
    gc_pool_mlp<<<n_graphs, HID, 0, stream>>>(buf1, gptr, Wc1, bc1, Wc2, bc2, Wc3, bc3, out);
}

// Round 4
// 405.034 us; speedup vs baseline: 6.3372x; 1.1985x over previous
//
#include <hip/hip_runtime.h>

#define HID 128
#define NB 16        // nodes per matmul block
#define SCAN_T 256
#define SCAN_TILE 1024   // elements per scan block (4 per thread)

// ---------------- int degree histograms over edges ----------------
__global__ void gc_degree(const int* __restrict__ src, const int* __restrict__ dst,
                          int* __restrict__ ideg_out, int* __restrict__ ideg_in,
                          int n_edges) {
    int e = blockIdx.x * blockDim.x + threadIdx.x;
    if (e < n_edges) {
        atomicAdd(&ideg_out[src[e]], 1);
        atomicAdd(&ideg_in[dst[e]], 1);
    }
}

// ---------------- 3-phase device-wide exclusive scan ----------------
__global__ void gc_scan_part(const int* __restrict__ deg, int* __restrict__ bsum, int n) {
    int t = threadIdx.x;
    int base = blockIdx.x * SCAN_TILE + t * 4;
    int s = 0;
    if (base + 3 < n) {
        int4 v = *reinterpret_cast<const int4*>(deg + base);
        s = v.x + v.y + v.z + v.w;
    } else {
        for (int j = 0; j < 4; ++j) if (base + j < n) s += deg[base + j];
    }
    __shared__ int sh[SCAN_T];
    sh[t] = s; __syncthreads();
    for (int o = SCAN_T / 2; o > 0; o >>= 1) {
        if (t < o) sh[t] += sh[t + o];
        __syncthreads();
    }
    if (t == 0) bsum[blockIdx.x] = sh[0];
}

__global__ void gc_scan_mid(int* __restrict__ bsum, int nb) {
    int t = threadIdx.x;   // SCAN_T threads, nb <= SCAN_T
    __shared__ int sh[SCAN_T];
    int v = (t < nb) ? bsum[t] : 0;
    sh[t] = v; __syncthreads();
    for (int o = 1; o < SCAN_T; o <<= 1) {
        int u = (t >= o) ? sh[t - o] : 0;
        __syncthreads();
        sh[t] += u;
        __syncthreads();
    }
    if (t < nb) bsum[t] = sh[t] - v;   // exclusive
}

__global__ void gc_scan_final(const int* __restrict__ deg, const int* __restrict__ bsum,
                              int* __restrict__ row_ptr, int* __restrict__ cursor, int n) {
    int t = threadIdx.x;
    int base = blockIdx.x * SCAN_TILE + t * 4;
    int d[4] = {0, 0, 0, 0};
    if (base + 3 < n) {
        int4 v = *reinterpret_cast<const int4*>(deg + base);
        d[0] = v.x; d[1] = v.y; d[2] = v.z; d[3] = v.w;
    } else {
        for (int j = 0; j < 4; ++j) if (base + j < n) d[j] = deg[base + j];
    }
    int s = d[0] + d[1] + d[2] + d[3];
    __shared__ int sh[SCAN_T];
    sh[t] = s; __syncthreads();
    for (int o = 1; o < SCAN_T; o <<= 1) {   // inclusive scan of thread sums
        int u = (t >= o) ? sh[t - o] : 0;
        __syncthreads();
        sh[t] += u;
        __syncthreads();
    }
    int run = bsum[blockIdx.x] + sh[t] - s;  // exclusive prefix for this thread
    #pragma unroll
    for (int j = 0; j < 4; ++j) {
        int idx = base + j;
        if (idx < n) {
            cursor[idx] = run;
            run += d[j];
            row_ptr[idx + 1] = run;
        }
    }
    if (t == 0 && blockIdx.x == 0) row_ptr[0] = 0;
}

// ---------------- per-node norms ----------------
__global__ void gc_node(const int* __restrict__ ideg_out, const int* __restrict__ ideg_in,
                        float* __restrict__ norm_s, float* __restrict__ norm_d,
                        int n_nodes) {
    int n = blockIdx.x * blockDim.x + threadIdx.x;
    if (n < n_nodes) {
        norm_s[n] = rsqrtf(fmaxf((float)ideg_out[n], 1.0f));
        norm_d[n] = rsqrtf(fmaxf((float)ideg_in[n], 1.0f));
    }
}

// ---------------- graph_ptr via binary search (gid is sorted) ----------------
__global__ void gc_gptr(const int* __restrict__ gid, int* __restrict__ gptr,
                        int n_nodes, int n_graphs) {
    int g = threadIdx.x;                      // 0..255
    int lo = 0, hi = n_nodes;
    while (lo < hi) {                         // lower_bound(gid, g)
        int mid = (lo + hi) >> 1;
        if (gid[mid] < g) lo = mid + 1; else hi = mid;
    }
    gptr[g] = lo;
    if (g == 0) gptr[n_graphs] = n_nodes;
}

// ---------------- CSR fill: edge_src bucketed by dst ----------------
__global__ void gc_fill(const int* __restrict__ src, const int* __restrict__ dst,
                        int* __restrict__ cursor, int* __restrict__ edge_src,
                        int n_edges) {
    int e = blockIdx.x * blockDim.x + threadIdx.x;
    if (e < n_edges) {
        int pos = atomicAdd(&cursor[dst[e]], 1);
        edge_src[pos] = src[e];
    }
}

// ---------------- out[n,:] = (X[n,:] * norm_s[n]) @ W ----------------
__global__ void gc_matmul(const float* __restrict__ X, const float* __restrict__ norm_s,
                          const float* __restrict__ W, float* __restrict__ out,
                          int n_nodes) {
    __shared__ float xs[NB][HID];
    int c = threadIdx.x;          // 0..127
    int n0 = blockIdx.x * NB;
    #pragma unroll
    for (int i = 0; i < NB; ++i) {
        int n = n0 + i;
        float v = 0.0f;
        if (n < n_nodes) v = X[(size_t)n * HID + c] * norm_s[n];
        xs[i][c] = v;
    }
    __syncthreads();
    float acc[NB];
    #pragma unroll
    for (int i = 0; i < NB; ++i) acc[i] = 0.0f;
    for (int k = 0; k < HID; ++k) {
        float wv = W[(size_t)k * HID + c];
        #pragma unroll
        for (int i = 0; i < NB; ++i) acc[i] += xs[i][k] * wv;  // xs broadcast read
    }
    #pragma unroll
    for (int i = 0; i < NB; ++i) {
        int n = n0 + i;
        if (n < n_nodes) out[(size_t)n * HID + c] = acc[i];
    }
}

// ------- gather + norm + bias + relu: 32 lanes per dst node, float4 cols -------
__global__ void gc_gather(const float* __restrict__ HW, const int* __restrict__ row_ptr,
                          const int* __restrict__ edge_src, const float* __restrict__ norm_d,
                          const float* __restrict__ b, float* __restrict__ out,
                          int n_nodes) {
    int node = blockIdx.x * 8 + (threadIdx.x >> 5);
    if (node >= n_nodes) return;
    int q = (threadIdx.x & 31) << 2;          // float4 column offset
    int beg = row_ptr[node], end = row_ptr[node + 1];
    float ax = 0.f, ay = 0.f, az = 0.f, aw = 0.f;
    int e = beg;
    for (; e + 1 < end; e += 2) {             // 2 independent rows in flight
        int s0 = edge_src[e], s1 = edge_src[e + 1];
        const float4 v0 = *reinterpret_cast<const float4*>(HW + (size_t)s0 * HID + q);
        const float4 v1 = *reinterpret_cast<const float4*>(HW + (size_t)s1 * HID + q);
        ax += v0.x + v1.x; ay += v0.y + v1.y;
        az += v0.z + v1.z; aw += v0.w + v1.w;
    }
    if (e < end) {
        int s0 = edge_src[e];
        const float4 v0 = *reinterpret_cast<const float4*>(HW + (size_t)s0 * HID + q);
        ax += v0.x; ay += v0.y; az += v0.z; aw += v0.w;
    }
    float nd = norm_d[node];
    const float4 bv = *reinterpret_cast<const float4*>(b + q);
    float4 r;
    r.x = fmaxf(ax * nd + bv.x, 0.0f);
    r.y = fmaxf(ay * nd + bv.y, 0.0f);
    r.z = fmaxf(az * nd + bv.z, 0.0f);
    r.w = fmaxf(aw * nd + bv.w, 0.0f);
    *reinterpret_cast<float4*>(out + (size_t)node * HID + q) = r;
}

// ------- fused mean-pool + MLP head: one block per graph, no atomics -------
__global__ void gc_pool_mlp(const float* __restrict__ h2, const int* __restrict__ gptr,
                            const float* __restrict__ Wc1, const float* __restrict__ bc1,
                            const float* __restrict__ Wc2, const float* __restrict__ bc2,
                            const float* __restrict__ Wc3, const float* __restrict__ bc3,
                            float* __restrict__ out) {
    int g = blockIdx.x;
    int c = threadIdx.x;   // 0..127
    int beg = gptr[g], end = gptr[g + 1];
    float s = 0.0f;
    for (int n = beg; n < end; ++n) s += h2[(size_t)n * HID + c];  // coalesced rows
    float inv = 1.0f / fmaxf((float)(end - beg), 1.0f);
    __shared__ float x[HID];
    __shared__ float y[HID];
    __shared__ float red[HID];
    x[c] = s * inv;
    __syncthreads();
    float a = bc1[c];
    for (int k = 0; k < HID; ++k) a += x[k] * Wc1[(size_t)k * HID + c];
    y[c] = fmaxf(a, 0.0f);
    __syncthreads();
    float a2 = bc2[c];
    for (int k = 0; k < HID; ++k) a2 += y[k] * Wc2[(size_t)k * HID + c];
    float z = fmaxf(a2, 0.0f);
    red[c] = z * Wc3[c];    // Wc3 is [128,1]
    __syncthreads();
    for (int sred = 64; sred > 0; sred >>= 1) {
        if (c < sred) red[c] += red[c + sred];
        __syncthreads();
    }
    if (c == 0) out[g] = red[0] + bc3[0];
}

extern "C" void kernel_launch(void* const* d_in, const int* in_sizes, int n_in,
                              void* d_out, int out_size, void* d_ws, size_t ws_size,
                              hipStream_t stream) {
    const float* h    = (const float*)d_in[0];
    const int*   src  = (const int*)d_in[1];
    const int*   dst  = (const int*)d_in[2];
    const int*   gid  = (const int*)d_in[3];
    const float* W1   = (const float*)d_in[4];
    const float* b1   = (const float*)d_in[5];
    const float* W2   = (const float*)d_in[6];
    const float* b2   = (const float*)d_in[7];
    const float* Wc1  = (const float*)d_in[8];
    const float* bc1  = (const float*)d_in[9];
    const float* Wc2  = (const float*)d_in[10];
    const float* bc2  = (const float*)d_in[11];
    const float* Wc3  = (const float*)d_in[12];
    const float* bc3  = (const float*)d_in[13];
    float* out = (float*)d_out;

    const int n_nodes  = in_sizes[0] / HID;   // 40000
    const int n_edges  = in_sizes[1];         // 640000
    const int n_graphs = 256;

    char* wsb = (char*)d_ws;
    size_t off = 0;
    auto alloc = [&](size_t elems) { void* p = wsb + off; off += elems * 4; return p; };

    const int scan_blocks = (n_nodes + SCAN_TILE - 1) / SCAN_TILE;   // 40

    int*   ideg_out = (int*)alloc(n_nodes);
    int*   ideg_in  = (int*)alloc(n_nodes);
    float* norm_s   = (float*)alloc(n_nodes);
    float* norm_d   = (float*)alloc(n_nodes);
    int*   row_ptr  = (int*)alloc(n_nodes + 1);
    int*   cursor   = (int*)alloc(n_nodes);
    int*   edge_src = (int*)alloc(n_edges);
    int*   gptr     = (int*)alloc(n_graphs + 1);
    int*   bsum     = (int*)alloc(scan_blocks);
    float* buf0     = (float*)alloc((size_t)n_nodes * HID);
    float* buf1     = (float*)alloc((size_t)n_nodes * HID);

    // zero the int degree histograms only
    hipMemsetAsync(ideg_out, 0, 2 * n_nodes * sizeof(int), stream);

    gc_degree<<<(n_edges + 255) / 256, 256, 0, stream>>>(src, dst, ideg_out, ideg_in, n_edges);
    gc_scan_part<<<scan_blocks, SCAN_T, 0, stream>>>(ideg_in, bsum, n_nodes);
    gc_scan_mid<<<1, SCAN_T, 0, stream>>>(bsum, scan_blocks);
    gc_scan_final<<<scan_blocks, SCAN_T, 0, stream>>>(ideg_in, bsum, row_ptr, cursor, n_nodes);
    gc_node<<<(n_nodes + 255) / 256, 256, 0, stream>>>(ideg_out, ideg_in, norm_s, norm_d, n_nodes);
    gc_gptr<<<1, n_graphs, 0, stream>>>(gid, gptr, n_nodes, n_graphs);
    gc_fill<<<(n_edges + 255) / 256, 256, 0, stream>>>(src, dst, cursor, edge_src, n_edges);

    const int mm_grid = (n_nodes + NB - 1) / NB;
    const int ga_grid = (n_nodes + 7) / 8;

    // ----- layer 1 -----
    gc_matmul<<<mm_grid, HID, 0, stream>>>(h, norm_s, W1, buf0, n_nodes);
    gc_gather<<<ga_grid, 256, 0, stream>>>(buf0, row_ptr, edge_src, norm_d, b1, buf1, n_nodes);

    // ----- layer 2 -----
    gc_matmul<<<mm_grid, HID, 0, stream>>>(buf1, norm_s, W2, buf0, n_nodes);
    gc_gather<<<ga_grid, 256, 0, stream>>>(buf0, row_ptr, edge_src, norm_d, b2, buf1, n_nodes);

    // ----- fused pooling + MLP head -----
    gc_pool_mlp<<<n_graphs, HID, 0, stream>>>(buf1, gptr, Wc1, bc1, Wc2, bc2, Wc3, bc3, out);
}

// Round 5
// 364.794 us; speedup vs baseline: 7.0362x; 1.1103x over previous
//
#include <hip/hip_runtime.h>

#define HID 128
#define NB 16        // nodes per matmul block
#define SCAN_T 256
#define SCAN_TILE 1024   // elements per scan block (4 per thread)

typedef unsigned int uint;
typedef unsigned short ushort;

// float -> bf16 with round-to-nearest-even
static __device__ __forceinline__ ushort f2bf(float f) {
    uint u = __float_as_uint(f);
    u += 0x7fffu + ((u >> 16) & 1u);
    return (ushort)(u >> 16);
}

// ---------------- int degree histograms over edges ----------------
__global__ void gc_degree(const int* __restrict__ src, const int* __restrict__ dst,
                          int* __restrict__ ideg_out, int* __restrict__ ideg_in,
                          int n_edges) {
    int e = blockIdx.x * blockDim.x + threadIdx.x;
    if (e < n_edges) {
        atomicAdd(&ideg_out[src[e]], 1);
        atomicAdd(&ideg_in[dst[e]], 1);
    }
}

// ---------------- 3-phase device-wide exclusive scan ----------------
__global__ void gc_scan_part(const int* __restrict__ deg, int* __restrict__ bsum, int n) {
    int t = threadIdx.x;
    int base = blockIdx.x * SCAN_TILE + t * 4;
    int s = 0;
    if (base + 3 < n) {
        int4 v = *reinterpret_cast<const int4*>(deg + base);
        s = v.x + v.y + v.z + v.w;
    } else {
        for (int j = 0; j < 4; ++j) if (base + j < n) s += deg[base + j];
    }
    __shared__ int sh[SCAN_T];
    sh[t] = s; __syncthreads();
    for (int o = SCAN_T / 2; o > 0; o >>= 1) {
        if (t < o) sh[t] += sh[t + o];
        __syncthreads();
    }
    if (t == 0) bsum[blockIdx.x] = sh[0];
}

__global__ void gc_scan_mid(int* __restrict__ bsum, int nb) {
    int t = threadIdx.x;   // SCAN_T threads, nb <= SCAN_T
    __shared__ int sh[SCAN_T];
    int v = (t < nb) ? bsum[t] : 0;
    sh[t] = v; __syncthreads();
    for (int o = 1; o < SCAN_T; o <<= 1) {
        int u = (t >= o) ? sh[t - o] : 0;
        __syncthreads();
        sh[t] += u;
        __syncthreads();
    }
    if (t < nb) bsum[t] = sh[t] - v;   // exclusive
}

__global__ void gc_scan_final(const int* __restrict__ deg, const int* __restrict__ bsum,
                              int* __restrict__ row_ptr, int* __restrict__ cursor, int n) {
    int t = threadIdx.x;
    int base = blockIdx.x * SCAN_TILE + t * 4;
    int d[4] = {0, 0, 0, 0};
    if (base + 3 < n) {
        int4 v = *reinterpret_cast<const int4*>(deg + base);
        d[0] = v.x; d[1] = v.y; d[2] = v.z; d[3] = v.w;
    } else {
        for (int j = 0; j < 4; ++j) if (base + j < n) d[j] = deg[base + j];
    }
    int s = d[0] + d[1] + d[2] + d[3];
    __shared__ int sh[SCAN_T];
    sh[t] = s; __syncthreads();
    for (int o = 1; o < SCAN_T; o <<= 1) {   // inclusive scan of thread sums
        int u = (t >= o) ? sh[t - o] : 0;
        __syncthreads();
        sh[t] += u;
        __syncthreads();
    }
    int run = bsum[blockIdx.x] + sh[t] - s;  // exclusive prefix for this thread
    #pragma unroll
    for (int j = 0; j < 4; ++j) {
        int idx = base + j;
        if (idx < n) {
            cursor[idx] = run;
            run += d[j];
            row_ptr[idx + 1] = run;
        }
    }
    if (t == 0 && blockIdx.x == 0) row_ptr[0] = 0;
}

// ---------------- per-node norms ----------------
__global__ void gc_node(const int* __restrict__ ideg_out, const int* __restrict__ ideg_in,
                        float* __restrict__ norm_s, float* __restrict__ norm_d,
                        int n_nodes) {
    int n = blockIdx.x * blockDim.x + threadIdx.x;
    if (n < n_nodes) {
        norm_s[n] = rsqrtf(fmaxf((float)ideg_out[n], 1.0f));
        norm_d[n] = rsqrtf(fmaxf((float)ideg_in[n], 1.0f));
    }
}

// ---------------- graph_ptr via binary search (gid is sorted) ----------------
__global__ void gc_gptr(const int* __restrict__ gid, int* __restrict__ gptr,
                        int n_nodes, int n_graphs) {
    int g = threadIdx.x;                      // 0..255
    int lo = 0, hi = n_nodes;
    while (lo < hi) {                         // lower_bound(gid, g)
        int mid = (lo + hi) >> 1;
        if (gid[mid] < g) lo = mid + 1; else hi = mid;
    }
    gptr[g] = lo;
    if (g == 0) gptr[n_graphs] = n_nodes;
}

// ---------------- CSR fill: edge_src bucketed by dst ----------------
__global__ void gc_fill(const int* __restrict__ src, const int* __restrict__ dst,
                        int* __restrict__ cursor, int* __restrict__ edge_src,
                        int n_edges) {
    int e = blockIdx.x * blockDim.x + threadIdx.x;
    if (e < n_edges) {
        int pos = atomicAdd(&cursor[dst[e]], 1);
        edge_src[pos] = src[e];
    }
}

// ---------------- out[n,:] = bf16((X[n,:] * norm_s[n]) @ W) ----------------
__global__ void gc_matmul(const float* __restrict__ X, const float* __restrict__ norm_s,
                          const float* __restrict__ W, ushort* __restrict__ out,
                          int n_nodes) {
    __shared__ float xs[NB][HID];
    int c = threadIdx.x;          // 0..127
    int n0 = blockIdx.x * NB;
    #pragma unroll
    for (int i = 0; i < NB; ++i) {
        int n = n0 + i;
        float v = 0.0f;
        if (n < n_nodes) v = X[(size_t)n * HID + c] * norm_s[n];
        xs[i][c] = v;
    }
    __syncthreads();
    float acc[NB];
    #pragma unroll
    for (int i = 0; i < NB; ++i) acc[i] = 0.0f;
    for (int k = 0; k < HID; ++k) {
        float wv = W[(size_t)k * HID + c];
        #pragma unroll
        for (int i = 0; i < NB; ++i) acc[i] += xs[i][k] * wv;  // xs broadcast read
    }
    #pragma unroll
    for (int i = 0; i < NB; ++i) {
        int n = n0 + i;
        if (n < n_nodes) out[(size_t)n * HID + c] = f2bf(acc[i]);
    }
}

// --- gather(bf16 rows) + norm + bias + relu: 16 lanes per dst node, 16B/lane ---
__global__ void gc_gather(const ushort* __restrict__ HW, const int* __restrict__ row_ptr,
                          const int* __restrict__ edge_src, const float* __restrict__ norm_d,
                          const float* __restrict__ b, float* __restrict__ out,
                          int n_nodes) {
    int node = blockIdx.x * 16 + (threadIdx.x >> 4);
    if (node >= n_nodes) return;
    int q = (threadIdx.x & 15) << 3;          // bf16 element offset (8 per lane)
    int beg = row_ptr[node], end = row_ptr[node + 1];
    float a[8];
    #pragma unroll
    for (int j = 0; j < 8; ++j) a[j] = 0.0f;

    auto accum = [&](uint4 u) {
        a[0] += __uint_as_float(u.x << 16);
        a[1] += __uint_as_float(u.x & 0xffff0000u);
        a[2] += __uint_as_float(u.y << 16);
        a[3] += __uint_as_float(u.y & 0xffff0000u);
        a[4] += __uint_as_float(u.z << 16);
        a[5] += __uint_as_float(u.z & 0xffff0000u);
        a[6] += __uint_as_float(u.w << 16);
        a[7] += __uint_as_float(u.w & 0xffff0000u);
    };

    int e = beg;
    for (; e + 1 < end; e += 2) {             // 2 independent 16B loads in flight
        int s0 = edge_src[e], s1 = edge_src[e + 1];
        uint4 u0 = *reinterpret_cast<const uint4*>(HW + (size_t)s0 * HID + q);
        uint4 u1 = *reinterpret_cast<const uint4*>(HW + (size_t)s1 * HID + q);
        accum(u0);
        accum(u1);
    }
    if (e < end) {
        int s0 = edge_src[e];
        uint4 u0 = *reinterpret_cast<const uint4*>(HW + (size_t)s0 * HID + q);
        accum(u0);
    }

    float nd = norm_d[node];
    float4 r0, r1;
    const float4 bv0 = *reinterpret_cast<const float4*>(b + q);
    const float4 bv1 = *reinterpret_cast<const float4*>(b + q + 4);
    r0.x = fmaxf(a[0] * nd + bv0.x, 0.0f);
    r0.y = fmaxf(a[1] * nd + bv0.y, 0.0f);
    r0.z = fmaxf(a[2] * nd + bv0.z, 0.0f);
    r0.w = fmaxf(a[3] * nd + bv0.w, 0.0f);
    r1.x = fmaxf(a[4] * nd + bv1.x, 0.0f);
    r1.y = fmaxf(a[5] * nd + bv1.y, 0.0f);
    r1.z = fmaxf(a[6] * nd + bv1.z, 0.0f);
    r1.w = fmaxf(a[7] * nd + bv1.w, 0.0f);
    *reinterpret_cast<float4*>(out + (size_t)node * HID + q) = r0;
    *reinterpret_cast<float4*>(out + (size_t)node * HID + q + 4) = r1;
}

// ------- fused mean-pool + MLP head: one block per graph, no atomics -------
__global__ void gc_pool_mlp(const float* __restrict__ h2, const int* __restrict__ gptr,
                            const float* __restrict__ Wc1, const float* __restrict__ bc1,
                            const float* __restrict__ Wc2, const float* __restrict__ bc2,
                            const float* __restrict__ Wc3, const float* __restrict__ bc3,
                            float* __restrict__ out) {
    int g = blockIdx.x;
    int c = threadIdx.x;   // 0..127
    int beg = gptr[g], end = gptr[g + 1];
    float s = 0.0f;
    for (int n = beg; n < end; ++n) s += h2[(size_t)n * HID + c];  // coalesced rows
    float inv = 1.0f / fmaxf((float)(end - beg), 1.0f);
    __shared__ float x[HID];
    __shared__ float y[HID];
    __shared__ float red[HID];
    x[c] = s * inv;
    __syncthreads();
    float a = bc1[c];
    for (int k = 0; k < HID; ++k) a += x[k] * Wc1[(size_t)k * HID + c];
    y[c] = fmaxf(a, 0.0f);
    __syncthreads();
    float a2 = bc2[c];
    for (int k = 0; k < HID; ++k) a2 += y[k] * Wc2[(size_t)k * HID + c];
    float z = fmaxf(a2, 0.0f);
    red[c] = z * Wc3[c];    // Wc3 is [128,1]
    __syncthreads();
    for (int sred = 64; sred > 0; sred >>= 1) {
        if (c < sred) red[c] += red[c + sred];
        __syncthreads();
    }
    if (c == 0) out[g] = red[0] + bc3[0];
}

extern "C" void kernel_launch(void* const* d_in, const int* in_sizes, int n_in,
                              void* d_out, int out_size, void* d_ws, size_t ws_size,
                              hipStream_t stream) {
    const float* h    = (const float*)d_in[0];
    const int*   src  = (const int*)d_in[1];
    const int*   dst  = (const int*)d_in[2];
    const int*   gid  = (const int*)d_in[3];
    const float* W1   = (const float*)d_in[4];
    const float* b1   = (const float*)d_in[5];
    const float* W2   = (const float*)d_in[6];
    const float* b2   = (const float*)d_in[7];
    const float* Wc1  = (const float*)d_in[8];
    const float* bc1  = (const float*)d_in[9];
    const float* Wc2  = (const float*)d_in[10];
    const float* bc2  = (const float*)d_in[11];
    const float* Wc3  = (const float*)d_in[12];
    const float* bc3  = (const float*)d_in[13];
    float* out = (float*)d_out;

    const int n_nodes  = in_sizes[0] / HID;   // 40000
    const int n_edges  = in_sizes[1];         // 640000
    const int n_graphs = 256;

    char* wsb = (char*)d_ws;
    size_t off = 0;
    auto alloc = [&](size_t bytes) {
        void* p = wsb + off;
        off += (bytes + 15) & ~(size_t)15;    // 16B-align every buffer
        return p;
    };

    const int scan_blocks = (n_nodes + SCAN_TILE - 1) / SCAN_TILE;   // 40

    int*    ideg_out = (int*)alloc(n_nodes * 4);
    int*    ideg_in  = (int*)alloc(n_nodes * 4);
    float*  norm_s   = (float*)alloc(n_nodes * 4);
    float*  norm_d   = (float*)alloc(n_nodes * 4);
    int*    row_ptr  = (int*)alloc((n_nodes + 1) * 4);
    int*    cursor   = (int*)alloc(n_nodes * 4);
    int*    edge_src = (int*)alloc(n_edges * 4);
    int*    gptr     = (int*)alloc((n_graphs + 1) * 4);
    int*    bsum     = (int*)alloc(scan_blocks * 4);
    ushort* buf0     = (ushort*)alloc((size_t)n_nodes * HID * 2);  // bf16 HW
    float*  buf1     = (float*)alloc((size_t)n_nodes * HID * 4);   // fp32 h1/h2

    // zero the int degree histograms only
    hipMemsetAsync(ideg_out, 0, 2 * n_nodes * sizeof(int), stream);

    gc_degree<<<(n_edges + 255) / 256, 256, 0, stream>>>(src, dst, ideg_out, ideg_in, n_edges);
    gc_scan_part<<<scan_blocks, SCAN_T, 0, stream>>>(ideg_in, bsum, n_nodes);
    gc_scan_mid<<<1, SCAN_T, 0, stream>>>(bsum, scan_blocks);
    gc_scan_final<<<scan_blocks, SCAN_T, 0, stream>>>(ideg_in, bsum, row_ptr, cursor, n_nodes);
    gc_node<<<(n_nodes + 255) / 256, 256, 0, stream>>>(ideg_out, ideg_in, norm_s, norm_d, n_nodes);
    gc_gptr<<<1, n_graphs, 0, stream>>>(gid, gptr, n_nodes, n_graphs);
    gc_fill<<<(n_edges + 255) / 256, 256, 0, stream>>>(src, dst, cursor, edge_src, n_edges);

    const int mm_grid = (n_nodes + NB - 1) / NB;
    const int ga_grid = (n_nodes + 15) / 16;

    // ----- layer 1 -----
    gc_matmul<<<mm_grid, HID, 0, stream>>>(h, norm_s, W1, buf0, n_nodes);
    gc_gather<<<ga_grid, 256, 0, stream>>>(buf0, row_ptr, edge_src, norm_d, b1, buf1, n_nodes);

    // ----- layer 2 -----
    gc_matmul<<<mm_grid, HID, 0, stream>>>(buf1, norm_s, W2, buf0, n_nodes);
    gc_gather<<<ga_grid, 256, 0, stream>>>(buf0, row_ptr, edge_src, norm_d, b2, buf1, n_nodes);

    // ----- fused pooling + MLP head -----
    gc_pool_mlp<<<n_graphs, HID, 0, stream>>>(buf1, gptr, Wc1, bc1, Wc2, bc2, Wc3, bc3, out);
}